// Round 8
// baseline (279.347 us; speedup 1.0000x reference)
//
#include <hip/hip_runtime.h>
#include <math.h>

// Problem constants
constexpr int B_   = 2;
constexpr int S_   = 2048;
constexpr int HID_ = 512;
constexpr int H_   = 8;
constexpr int DH_  = 64;
constexpr int M_   = B_ * S_;

typedef unsigned short ushort_t;
typedef unsigned int   uint_t;
typedef __attribute__((ext_vector_type(4))) float  f32x4;
typedef __attribute__((ext_vector_type(8))) __bf16 bf16x8;
typedef __attribute__((ext_vector_type(4))) uint_t u32x4;

#define MFMA16(A, Bv, C) __builtin_amdgcn_mfma_f32_16x16x32_bf16( \
    __builtin_bit_cast(bf16x8, (A)), __builtin_bit_cast(bf16x8, (Bv)), (C), 0, 0, 0)

// Split fp32 x -> hi bf16 (truncate) + lo bf16 (truncate of exact residual).
__device__ __forceinline__ uint2 splitPair(float x0, float x1) {
    uint_t b0 = __float_as_uint(x0), b1 = __float_as_uint(x1);
    uint_t hi = (b0 >> 16) | (b1 & 0xFFFF0000u);
    float h0 = __uint_as_float(b0 & 0xFFFF0000u);
    float h1 = __uint_as_float(b1 & 0xFFFF0000u);
    uint_t l0 = __float_as_uint(x0 - h0), l1 = __float_as_uint(x1 - h1);
    uint_t lo = (l0 >> 16) | (l1 & 0xFFFF0000u);
    return make_uint2(hi, lo);
}

__device__ __forceinline__ void splitOne(float x, ushort_t& hi, ushort_t& lo) {
    uint_t b = __float_as_uint(x);
    hi = (ushort_t)(b >> 16);
    float h = __uint_as_float(b & 0xFFFF0000u);
    lo = (ushort_t)(__float_as_uint(x - h) >> 16);
}

// ---------------------------------------------------------------------------
// Split-bf16 MFMA GEMM, BM=128 BN=64 BK=32, reg-prefetch pipeline.
// 256 thr = 4 waves (2x2); wave owns 64x32 (mt=4, nt=2) -> 12 b128 LDS reads
// per 24 MFMAs per iter (2x better amortization than 32x32 wave tile).
// MODE 0: fp32 out[m][n]
// MODE 1: Q — euler(delta)+scale(1/8) -> split planes [b][h][s][d]
// MODE 2: K — euler(delta)           -> split planes [b][h][s][d]
// MODE 3: V —                         -> split planes [b][h][d][s] (V^T)
// ---------------------------------------------------------------------------
template <int MODE>
__device__ __forceinline__ void gemm_mfma_body(const float* __restrict__ A,
                                               const float* __restrict__ W,
                                               const float* __restrict__ bias,
                                               ushort_t* __restrict__ outHi,
                                               ushort_t* __restrict__ outLo,
                                               float* __restrict__ outF,
                                               const float* __restrict__ delta)
{
    constexpr int K_ = HID_;
    __shared__ __align__(16) ushort_t Ah[128][40], Al[128][40];
    __shared__ __align__(16) ushort_t Bh[64][40],  Bl[64][40];

    const int t    = threadIdx.x;
    const int lane = t & 63;
    const int wid  = t >> 6;
    const int wr   = wid >> 1;      // M half (64 rows)
    const int wc   = wid & 1;       // N half (32 cols)
    const int a    = lane & 15;
    const int g    = lane >> 4;
    const int bm   = blockIdx.x * 128;
    const int bn   = blockIdx.y * 64;

    // staging: A 128x32 -> thread handles row t>>1, 16 cols at (t&1)*16
    //          W  64x32 -> thread handles row t>>2,  8 cols at (t&3)*8
    const int arow = t >> 1, acol = (t & 1) * 16;
    const int wrow = t >> 2, wcol = (t & 3) * 8;
    const float* Ap = A + (size_t)(bm + arow) * K_ + acol;
    const float* Wp = W + (size_t)(bn + wrow) * K_ + wcol;

    float4 ra0 = ((const float4*)Ap)[0], ra1 = ((const float4*)Ap)[1];
    float4 ra2 = ((const float4*)Ap)[2], ra3 = ((const float4*)Ap)[3];
    float4 rw0 = ((const float4*)Wp)[0], rw1 = ((const float4*)Wp)[1];

    f32x4 acc[4][2];
#pragma unroll
    for (int mt = 0; mt < 4; ++mt)
#pragma unroll
        for (int nt = 0; nt < 2; ++nt)
#pragma unroll
            for (int r = 0; r < 4; ++r) acc[mt][nt][r] = 0.f;

    for (int k0 = 0; k0 < K_; k0 += 32) {
        __syncthreads();   // previous iter done reading LDS
        {
            const uint2 s0 = splitPair(ra0.x, ra0.y), s1 = splitPair(ra0.z, ra0.w);
            const uint2 s2 = splitPair(ra1.x, ra1.y), s3 = splitPair(ra1.z, ra1.w);
            *(u32x4*)&Ah[arow][acol] = u32x4{s0.x, s1.x, s2.x, s3.x};
            *(u32x4*)&Al[arow][acol] = u32x4{s0.y, s1.y, s2.y, s3.y};
            const uint2 s4 = splitPair(ra2.x, ra2.y), s5 = splitPair(ra2.z, ra2.w);
            const uint2 s6 = splitPair(ra3.x, ra3.y), s7 = splitPair(ra3.z, ra3.w);
            *(u32x4*)&Ah[arow][acol + 8] = u32x4{s4.x, s5.x, s6.x, s7.x};
            *(u32x4*)&Al[arow][acol + 8] = u32x4{s4.y, s5.y, s6.y, s7.y};
            const uint2 t0 = splitPair(rw0.x, rw0.y), t1 = splitPair(rw0.z, rw0.w);
            const uint2 t2 = splitPair(rw1.x, rw1.y), t3 = splitPair(rw1.z, rw1.w);
            *(u32x4*)&Bh[wrow][wcol] = u32x4{t0.x, t1.x, t2.x, t3.x};
            *(u32x4*)&Bl[wrow][wcol] = u32x4{t0.y, t1.y, t2.y, t3.y};
        }
        if (k0 + 32 < K_) {   // prefetch next tile (latency hides under MFMA)
            const float* pa = Ap + k0 + 32;
            const float* pw = Wp + k0 + 32;
            ra0 = ((const float4*)pa)[0]; ra1 = ((const float4*)pa)[1];
            ra2 = ((const float4*)pa)[2]; ra3 = ((const float4*)pa)[3];
            rw0 = ((const float4*)pw)[0]; rw1 = ((const float4*)pw)[1];
        }
        __syncthreads();

        u32x4 afh[4], afl[4], bfh[2], bfl[2];
#pragma unroll
        for (int mt = 0; mt < 4; ++mt) {
            const int ar = wr * 64 + mt * 16 + a;
            afh[mt] = *(const u32x4*)&Ah[ar][g * 8];
            afl[mt] = *(const u32x4*)&Al[ar][g * 8];
        }
#pragma unroll
        for (int nt = 0; nt < 2; ++nt) {
            const int br = wc * 32 + nt * 16 + a;
            bfh[nt] = *(const u32x4*)&Bh[br][g * 8];
            bfl[nt] = *(const u32x4*)&Bl[br][g * 8];
        }
#pragma unroll
        for (int nt = 0; nt < 2; ++nt)
#pragma unroll
            for (int mt = 0; mt < 4; ++mt) {
                acc[mt][nt] = MFMA16(afh[mt], bfh[nt], acc[mt][nt]);
                acc[mt][nt] = MFMA16(afh[mt], bfl[nt], acc[mt][nt]);
                acc[mt][nt] = MFMA16(afl[mt], bfh[nt], acc[mt][nt]);
            }
    }

    // ---- epilogue (D: row = g*4+r, col = a within each 16x16)
    const float del = (MODE == 1 || MODE == 2) ? delta[0] : 0.f;
#pragma unroll
    for (int mt = 0; mt < 4; ++mt) {
#pragma unroll
        for (int nt = 0; nt < 2; ++nt) {
            const int n  = bn + wc * 32 + nt * 16 + a;
            const float bb = bias[n];
            f32x4 vals;
#pragma unroll
            for (int r = 0; r < 4; ++r) vals[r] = acc[mt][nt][r] + bb;

            if (MODE == 0) {
#pragma unroll
                for (int r = 0; r < 4; ++r) {
                    const int m = bm + wr * 64 + mt * 16 + g * 4 + r;
                    outF[(size_t)m * HID_ + n] = vals[r];
                }
            } else if (MODE == 1 || MODE == 2) {
                const int d  = n & 63;
                const int h  = n >> 6;
                const float freq = exp2f(-(float)(d >> 1) * 0.4152410118609203f);
#pragma unroll
                for (int r = 0; r < 4; ++r) {
                    const int m = bm + wr * 64 + mt * 16 + g * 4 + r;
                    const int b = m >> 11, s = m & (S_ - 1);
                    const float val  = vals[r];
                    const float part = __shfl_xor(val, 1);
                    const float rr = (a & 1) ? part : val;
                    const float pp = (a & 1) ? val  : part;
                    const float lam = sqrtf(rr * rr + pp * pp);
                    const float th  = atan2f(pp, rr) * del + (float)s * freq;
                    float sn, cs;
                    sincosf(th, &sn, &cs);
                    float o = (a & 1) ? lam * sn : lam * cs;
                    if (MODE == 1) o *= 0.125f;   // 1/sqrt(DH) pre-applied to Q
                    ushort_t hi, lo;
                    splitOne(o, hi, lo);
                    const size_t idx = (((size_t)b * H_ + h) * S_ + s) * DH_ + d;
                    outHi[idx] = hi;
                    outLo[idx] = lo;
                }
            } else {   // MODE 3: V^T planes [b][h][d][s]
                const int d  = n & 63;
                const int h  = n >> 6;
                const int m0 = bm + wr * 64 + mt * 16 + g * 4;
                const int b  = m0 >> 11, s0 = m0 & (S_ - 1);
                const uint2 p01 = splitPair(vals[0], vals[1]);
                const uint2 p23 = splitPair(vals[2], vals[3]);
                const size_t idx = (((size_t)b * H_ + h) * DH_ + d) * S_ + s0;
                *(uint2*)&outHi[idx] = make_uint2(p01.x, p23.x);
                *(uint2*)&outLo[idx] = make_uint2(p01.y, p23.y);
            }
        }
    }
}

struct QkvPtrs {
    const float* A[3];
    const float* W[3];
    const float* bias[3];
    ushort_t*    hi[3];
    ushort_t*    lo[3];
    const float* del[2];
};

__global__ __launch_bounds__(256)
void gemm_qkv_kernel(QkvPtrs p)
{
    const int z = blockIdx.z;   // 0=q 1=k 2=v
    if (z == 0)      gemm_mfma_body<1>(p.A[0], p.W[0], p.bias[0], p.hi[0], p.lo[0], nullptr, p.del[0]);
    else if (z == 1) gemm_mfma_body<2>(p.A[1], p.W[1], p.bias[1], p.hi[1], p.lo[1], nullptr, p.del[1]);
    else             gemm_mfma_body<3>(p.A[2], p.W[2], p.bias[2], p.hi[2], p.lo[2], nullptr, nullptr);
}

__global__ __launch_bounds__(256)
void gemm_out_kernel(const float* __restrict__ A, const float* __restrict__ W,
                     const float* __restrict__ bias, float* __restrict__ out)
{
    gemm_mfma_body<0>(A, W, bias, nullptr, nullptr, out, nullptr);
}

// ---------------------------------------------------------------------------
// Flash attention (causal), split-bf16 MFMA, fp32 softmax, T14 reg-prefetch:
// next K/V tile's global loads issue before current tile's compute, ds_write
// after the next barrier — HBM latency hides under QK/softmax/PV.
// Inputs pre-split bf16 planes: Q/K [b][h][s][d], V [b][h][d][s]; Q pre-scaled.
// Grid (32, B*H), block 256 = 4 waves; wave w owns q-rows [qt*64+w*16, +16).
// ---------------------------------------------------------------------------
__global__ __launch_bounds__(256)
void attn_mfma_kernel(const ushort_t* __restrict__ qhi_g, const ushort_t* __restrict__ qlo_g,
                      const ushort_t* __restrict__ khi_g, const ushort_t* __restrict__ klo_g,
                      const ushort_t* __restrict__ vhi_g, const ushort_t* __restrict__ vlo_g,
                      float* __restrict__ hidden)
{
    __shared__ __align__(16) ushort_t Khi[64][72];
    __shared__ __align__(16) ushort_t Klo[64][72];
    __shared__ __align__(16) ushort_t Vhi[64][72];   // [dh][key]
    __shared__ __align__(16) ushort_t Vlo[64][72];
    __shared__ __align__(16) ushort_t Ph[4][16][72]; // per-wave [q][key]
    __shared__ __align__(16) ushort_t Pl[4][16][72];

    const int t    = threadIdx.x;
    const int lane = t & 63;
    const int wid  = t >> 6;
    const int a    = lane & 15;
    const int g    = lane >> 4;
    const int qt   = 31 - blockIdx.x;   // heavy tiles first (LPT)
    const int bh   = blockIdx.y;

    // Q fragments straight from split planes (pre-scaled)
    u32x4 qhi[2], qlo[2];
    {
        const size_t qrow = ((size_t)bh * S_ + (size_t)qt * 64 + wid * 16 + a) * DH_;
#pragma unroll
        for (int kit = 0; kit < 2; ++kit) {
            qhi[kit] = *(const u32x4*)&qhi_g[qrow + kit * 32 + g * 8];
            qlo[kit] = *(const u32x4*)&qlo_g[qrow + kit * 32 + g * 8];
        }
    }

    const ushort_t* Kbh = khi_g + (size_t)bh * S_ * DH_;
    const ushort_t* Kbl = klo_g + (size_t)bh * S_ * DH_;
    const ushort_t* Vbh = vhi_g + (size_t)bh * DH_ * S_;
    const ushort_t* Vbl = vlo_g + (size_t)bh * DH_ * S_;

    // staging geometry: 512 segs of 8 ushorts; thread handles segs t, t+256
    const int r0 = t >> 3,          c0 = (t & 7) * 8;
    const int r1 = (t + 256) >> 3,  c1 = ((t + 256) & 7) * 8;

    u32x4 rKh[2], rKl[2], rVh[2], rVl[2];
    auto loadKV = [&](int kt) {
        const size_t ko = (size_t)kt * 64 * DH_;
        const size_t vo = (size_t)kt * 64;
        rKh[0] = *(const u32x4*)&Kbh[ko + r0 * 64 + c0];
        rKh[1] = *(const u32x4*)&Kbh[ko + r1 * 64 + c1];
        rKl[0] = *(const u32x4*)&Kbl[ko + r0 * 64 + c0];
        rKl[1] = *(const u32x4*)&Kbl[ko + r1 * 64 + c1];
        rVh[0] = *(const u32x4*)&Vbh[vo + (size_t)r0 * S_ + c0];
        rVh[1] = *(const u32x4*)&Vbh[vo + (size_t)r1 * S_ + c1];
        rVl[0] = *(const u32x4*)&Vbl[vo + (size_t)r0 * S_ + c0];
        rVl[1] = *(const u32x4*)&Vbl[vo + (size_t)r1 * S_ + c1];
    };
    loadKV(0);

    f32x4 Oacc[4];
#pragma unroll
    for (int nt = 0; nt < 4; ++nt)
#pragma unroll
        for (int r = 0; r < 4; ++r) Oacc[nt][r] = 0.f;
    float mrow[4] = {-INFINITY, -INFINITY, -INFINITY, -INFINITY};
    float lrow[4] = {0.f, 0.f, 0.f, 0.f};

    for (int kt = 0; kt <= qt; ++kt) {
        __syncthreads();   // all waves done reading LDS of previous tile
        *(u32x4*)&Khi[r0][c0] = rKh[0];  *(u32x4*)&Khi[r1][c1] = rKh[1];
        *(u32x4*)&Klo[r0][c0] = rKl[0];  *(u32x4*)&Klo[r1][c1] = rKl[1];
        *(u32x4*)&Vhi[r0][c0] = rVh[0];  *(u32x4*)&Vhi[r1][c1] = rVh[1];
        *(u32x4*)&Vlo[r0][c0] = rVl[0];  *(u32x4*)&Vlo[r1][c1] = rVl[1];
        if (kt < qt) loadKV(kt + 1);     // prefetch next tile into regs
        __syncthreads();

        // ---- QK^T: D[q=(g*4+r)][key=a+16nt]
        f32x4 Sacc[4];
#pragma unroll
        for (int nt = 0; nt < 4; ++nt)
#pragma unroll
            for (int r = 0; r < 4; ++r) Sacc[nt][r] = 0.f;
#pragma unroll
        for (int kit = 0; kit < 2; ++kit) {
#pragma unroll
            for (int nt = 0; nt < 4; ++nt) {
                const u32x4 kbh = *(const u32x4*)&Khi[a + 16 * nt][kit * 32 + g * 8];
                const u32x4 kbl = *(const u32x4*)&Klo[a + 16 * nt][kit * 32 + g * 8];
                Sacc[nt] = MFMA16(qhi[kit], kbh, Sacc[nt]);
                Sacc[nt] = MFMA16(qhi[kit], kbl, Sacc[nt]);
                Sacc[nt] = MFMA16(qlo[kit], kbh, Sacc[nt]);
            }
        }

        // ---- causal mask + online softmax
        float sc[4][4];
        const int q0 = qt * 64 + wid * 16 + g * 4;
        const int k0 = kt * 64 + a;
#pragma unroll
        for (int nt = 0; nt < 4; ++nt)
#pragma unroll
            for (int r = 0; r < 4; ++r)
                sc[nt][r] = (k0 + 16 * nt <= q0 + r) ? Sacc[nt][r] : -INFINITY;

#pragma unroll
        for (int r = 0; r < 4; ++r) {
            float mr = fmaxf(fmaxf(sc[0][r], sc[1][r]), fmaxf(sc[2][r], sc[3][r]));
            mr = fmaxf(mr, __shfl_xor(mr, 1));
            mr = fmaxf(mr, __shfl_xor(mr, 2));
            mr = fmaxf(mr, __shfl_xor(mr, 4));
            mr = fmaxf(mr, __shfl_xor(mr, 8));
            const float mnew = fmaxf(mrow[r], mr);
            const float fac  = __expf(mrow[r] - mnew);
            mrow[r] = mnew;
            float ps = 0.f;
            const int q = g * 4 + r;
#pragma unroll
            for (int nt = 0; nt < 4; ++nt) {
                const float p = __expf(sc[nt][r] - mnew);
                ps += p;
                ushort_t phi, plo;
                splitOne(p, phi, plo);
                Ph[wid][q][a + 16 * nt] = phi;
                Pl[wid][q][a + 16 * nt] = plo;
            }
            lrow[r] = lrow[r] * fac + ps;
#pragma unroll
            for (int nt = 0; nt < 4; ++nt) Oacc[nt][r] *= fac;
        }

        // ---- PV: D[q][dh=a+16nt]
#pragma unroll
        for (int kit = 0; kit < 2; ++kit) {
            const u32x4 pah = *(const u32x4*)&Ph[wid][a][kit * 32 + g * 8];
            const u32x4 pal = *(const u32x4*)&Pl[wid][a][kit * 32 + g * 8];
#pragma unroll
            for (int nt = 0; nt < 4; ++nt) {
                const u32x4 vbh = *(const u32x4*)&Vhi[a + 16 * nt][kit * 32 + g * 8];
                const u32x4 vbl = *(const u32x4*)&Vlo[a + 16 * nt][kit * 32 + g * 8];
                Oacc[nt] = MFMA16(pah, vbh, Oacc[nt]);
                Oacc[nt] = MFMA16(pah, vbl, Oacc[nt]);
                Oacc[nt] = MFMA16(pal, vbh, Oacc[nt]);
            }
        }
    }

    // ---- epilogue
    float inv[4];
#pragma unroll
    for (int r = 0; r < 4; ++r) {
        float ls = lrow[r];
        ls += __shfl_xor(ls, 1);
        ls += __shfl_xor(ls, 2);
        ls += __shfl_xor(ls, 4);
        ls += __shfl_xor(ls, 8);
        inv[r] = 1.f / ls;
    }
    const int b = bh >> 3, h = bh & 7;
#pragma unroll
    for (int r = 0; r < 4; ++r) {
        const int qg = qt * 64 + wid * 16 + g * 4 + r;
        float* dst = hidden + ((size_t)b * S_ + qg) * HID_ + h * DH_ + a;
#pragma unroll
        for (int nt = 0; nt < 4; ++nt) dst[16 * nt] = Oacc[nt][r] * inv[r];
    }
}

// ---------------------------------------------------------------------------
// Launch
// ---------------------------------------------------------------------------
extern "C" void kernel_launch(void* const* d_in, const int* in_sizes, int n_in,
                              void* d_out, int out_size, void* d_ws, size_t ws_size,
                              hipStream_t stream)
{
    const float* q  = (const float*)d_in[0];
    const float* k  = (const float*)d_in[1];
    const float* v  = (const float*)d_in[2];
    const float* Wq = (const float*)d_in[3];
    const float* bq = (const float*)d_in[4];
    const float* Wk = (const float*)d_in[5];
    const float* bk = (const float*)d_in[6];
    const float* Wv = (const float*)d_in[7];
    const float* bv = (const float*)d_in[8];
    const float* Wo = (const float*)d_in[9];
    const float* bo = (const float*)d_in[10];
    const float* dq = (const float*)d_in[11];
    const float* dk = (const float*)d_in[12];
    float* out = (float*)d_out;

    // ws (32 MB): 6 ushort planes of TEN + fp32 hidden of TEN
    const size_t TEN = (size_t)B_ * S_ * HID_;   // 2,097,152
    ushort_t* qhi = (ushort_t*)d_ws;
    ushort_t* qlo = qhi + TEN;
    ushort_t* khi = qlo + TEN;
    ushort_t* klo = khi + TEN;
    ushort_t* vhi = klo + TEN;
    ushort_t* vlo = vhi + TEN;
    float* hidden = (float*)(vlo + TEN);

    QkvPtrs p;
    p.A[0] = q; p.W[0] = Wq; p.bias[0] = bq; p.hi[0] = qhi; p.lo[0] = qlo;
    p.A[1] = k; p.W[1] = Wk; p.bias[1] = bk; p.hi[1] = khi; p.lo[1] = klo;
    p.A[2] = v; p.W[2] = Wv; p.bias[2] = bv; p.hi[2] = vhi; p.lo[2] = vlo;
    p.del[0] = dq; p.del[1] = dk;

    gemm_qkv_kernel<<<dim3(M_ / 128, HID_ / 64, 3), 256, 0, stream>>>(p);
    attn_mfma_kernel<<<dim3(S_ / 64, B_ * H_), 256, 0, stream>>>(qhi, qlo, khi, klo, vhi, vlo, hidden);
    gemm_out_kernel<<<dim3(M_ / 128, HID_ / 64), 256, 0, stream>>>(hidden, Wo, bo, out);
}